// Round 20
// baseline (444.741 us; speedup 1.0000x reference)
//
#include <hip/hip_runtime.h>
#include <hip/hip_bf16.h>
#include <math.h>

#define NTOK 2048
#define HDIM 1024
#define NEXP 8
#define FDIM 3584
#define NHEADS 16
#define NLOW 204
#define NHIGH 204
#define BK 64
#define KSPLIT 8
#define KCH (FDIM / KSPLIT)   // 448

typedef __bf16 bf16x8 __attribute__((ext_vector_type(8)));
typedef float f32x4 __attribute__((ext_vector_type(4)));

// async global->LDS, 16B per lane; LDS dest wave-uniform base + lane*16
__device__ __forceinline__ void gload16(__hip_bfloat16* lds, const __hip_bfloat16* g)
{
    __builtin_amdgcn_global_load_lds(
        (const __attribute__((address_space(1))) unsigned int*)g,
        (__attribute__((address_space(3))) unsigned int*)lds, 16, 0, 0);
}

__device__ __forceinline__ void cvt8(const float* __restrict__ s,
                                     __hip_bfloat16* __restrict__ d)
{
    float4 a = *(const float4*)s;
    float4 b = *(const float4*)(s + 4);
    bf16x8 v;
    v[0] = (__bf16)a.x; v[1] = (__bf16)a.y; v[2] = (__bf16)a.z; v[3] = (__bf16)a.w;
    v[4] = (__bf16)b.x; v[5] = (__bf16)b.y; v[6] = (__bf16)b.z; v[7] = (__bf16)b.w;
    *(bf16x8*)d = v;
}

// ---------------- K0: fused prep: zero(out) + x->bf16 + w1->bf16 + w3->bf16 --
#define NZ   (NTOK * HDIM / 4)          // float4 zero stores
#define NX   (NTOK * HDIM / 8)          // x cvt8 units
#define NWT  (NEXP * FDIM * HDIM / 8)   // per-weight cvt8 units
__global__ __launch_bounds__(256) void k_prep(
    const float* __restrict__ x, const float* __restrict__ w1,
    const float* __restrict__ w3, float4* __restrict__ outz,
    __hip_bfloat16* __restrict__ xb, __hip_bfloat16* __restrict__ wb1,
    __hip_bfloat16* __restrict__ wb3)
{
    size_t gid = (size_t)blockIdx.x * 256 + threadIdx.x;
    size_t stride = (size_t)gridDim.x * 256;
    size_t total = (size_t)NZ + NX + 2 * (size_t)NWT;
    for (size_t i = gid; i < total; i += stride) {
        if (i < NZ) {
            outz[i] = make_float4(0.f, 0.f, 0.f, 0.f);
        } else if (i < (size_t)NZ + NX) {
            size_t j = (i - NZ) * 8;
            cvt8(x + j, xb + j);
        } else if (i < (size_t)NZ + NX + NWT) {
            size_t j = (i - NZ - NX) * 8;
            cvt8(w1 + j, wb1 + j);
        } else {
            size_t j = (i - NZ - NX - NWT) * 8;
            cvt8(w3 + j, wb3 + j);
        }
    }
}

// ---------------- K1: router logits + softmax top2 + L1 norm ----------------
__global__ __launch_bounds__(256) void k_router(
    const float* __restrict__ x, const float* __restrict__ gw,
    float* __restrict__ logits, float* __restrict__ l1,
    int* __restrict__ sel0, int* __restrict__ sel1,
    float* __restrict__ rw0, float* __restrict__ rw1)
{
    __shared__ float sgw[NEXP * HDIM];
    int tid = threadIdx.x;
    for (int i = tid; i < NEXP * HDIM; i += 256) sgw[i] = gw[i];
    __syncthreads();
    int wv = tid >> 6, lane = tid & 63;
    int t = blockIdx.x * 4 + wv;
    const float* xr = x + (size_t)t * HDIM;
    float acc[NEXP];
#pragma unroll
    for (int e = 0; e < NEXP; ++e) acc[e] = 0.f;
    float al1 = 0.f;
    for (int h = lane; h < HDIM; h += 64) {
        float xv = xr[h];
        al1 += fabsf(xv);
#pragma unroll
        for (int e = 0; e < NEXP; ++e) acc[e] += xv * sgw[e * HDIM + h];
    }
#pragma unroll
    for (int off = 32; off > 0; off >>= 1) {
#pragma unroll
        for (int e = 0; e < NEXP; ++e) acc[e] += __shfl_xor(acc[e], off);
        al1 += __shfl_xor(al1, off);
    }
    if (lane < NEXP) logits[t * NEXP + lane] = acc[lane];
    if (lane == 0) {
        l1[t] = al1;
        float m = acc[0];
#pragma unroll
        for (int e = 1; e < NEXP; ++e) m = fmaxf(m, acc[e]);
        float p[NEXP], s = 0.f;
#pragma unroll
        for (int e = 0; e < NEXP; ++e) { p[e] = expf(acc[e] - m); s += p[e]; }
        float inv = 1.f / s;
        float b0 = -1.f, b1 = -1.f; int i0 = 0, i1 = 0;
#pragma unroll
        for (int e = 0; e < NEXP; ++e) {
            float r = p[e] * inv;
            if (r > b0) { b1 = b0; i1 = i0; b0 = r; i0 = e; }
            else if (r > b1) { b1 = r; i1 = e; }
        }
        sel0[t] = i0; sel1[t] = i1; rw0[t] = b0; rw1[t] = b1;
    }
}

// ---------------- K2: attention-based token scores ----------------
__global__ __launch_bounds__(256) void k_attn(
    const float* __restrict__ attn, const float* __restrict__ l1,
    float* __restrict__ scores)
{
    int i = blockIdx.x, tid = threadIdx.x;
    float acc = 0.f;
    for (int h = 0; h < NHEADS; ++h) {
        const float4* p = (const float4*)(attn + ((size_t)h * NTOK + i) * NTOK);
        for (int j = tid; j < NTOK / 4; j += 256) {
            float4 v = p[j];
            acc += v.x + v.y + v.z + v.w;
        }
    }
    __shared__ float red[256];
    red[tid] = acc; __syncthreads();
    for (int s = 128; s > 0; s >>= 1) {
        if (tid < s) red[tid] += red[tid + s];
        __syncthreads();
    }
    if (tid == 0) scores[i] = red[0] / (16.f * (float)(NTOK - i)) * l1[i];
}

// ---------------- K3: exact stable-rank top-k masks + final routing weights --
__global__ __launch_bounds__(256) void k_rank(
    const float* __restrict__ scores, const float* __restrict__ rw0,
    const float* __restrict__ rw1, float* __restrict__ w0f, float* __restrict__ w1f)
{
    __shared__ float s[NTOK];
    int tid = threadIdx.x;
    for (int i = tid; i < NTOK; i += 256) s[i] = scores[i];
    __syncthreads();
    int t = blockIdx.x * 256 + tid;
    float st = s[t];
    int cl = 0, ch = 0;
    for (int j = 0; j < NTOK; ++j) {
        float sj = s[j];
        int tie = (sj == st) && (j < t);
        cl += (sj < st) || tie;
        ch += (sj > st) || tie;
    }
    bool in_low = cl < NLOW, keep = ch < NHIGH;
    float a = rw0[t], b = rw1[t];
    float n0 = 1.f, n1 = (b < 0.5f * a) ? 0.f : 1.f;
    if (in_low) { n0 = 0.f; n1 = 0.f; }
    if (keep)   { n0 = 1.f; n1 = 1.f; }
    a *= n0; b *= n1;
    float d = a + b;
    if (d > 0.f) { a /= d; b /= d; }
    w0f[t] = a; w1f[t] = b;
}

// ---------------- K4: per-expert token list build (deterministic) ----------
__global__ __launch_bounds__(512) void k_build(
    const int* __restrict__ sel0, const int* __restrict__ sel1,
    const float* __restrict__ w0f, const float* __restrict__ w1f,
    int* __restrict__ tok, float* __restrict__ wgt,
    int* __restrict__ counts, int* __restrict__ offs)
{
    int tid = threadIdx.x;
    int e = tid >> 6, lane = tid & 63;
    unsigned long long below = (1ull << lane) - 1ull;
    int base = 0;
    for (int r = 0; r < NTOK / 64; ++r) {
        int t = r * 64 + lane;
        bool f0 = (sel0[t] == e) && (w0f[t] > 0.f);
        unsigned long long m0 = __ballot(f0);
        if (f0) {
            int pos = base + __popcll(m0 & below);
            tok[e * NTOK + pos] = t; wgt[e * NTOK + pos] = w0f[t];
        }
        base += __popcll(m0);
        bool f1 = (sel1[t] == e) && (w1f[t] > 0.f);
        unsigned long long m1 = __ballot(f1);
        if (f1) {
            int pos = base + __popcll(m1 & below);
            tok[e * NTOK + pos] = t; wgt[e * NTOK + pos] = w1f[t];
        }
        base += __popcll(m1);
    }
    if (lane == 0) counts[e] = base;
    __syncthreads();
    if (tid == 0) {
        int o = 0;
        for (int i = 0; i < NEXP; ++i) { offs[i] = o; o += counts[i]; }
    }
}

// ---------------- K6: grouped GEMM phase 1 (+ w2 conversion at z==0) --------
// r11-proven geometry: 128M x 64F tile, BK=64, 4 waves (32 M-rows x 64 F each),
// single-buffered LDS via global_load_lds, XOR-swizzle. blockIdx.z==0 blocks
// (dispatched FIRST) convert w2->bf16; GEMM blocks use e = z-1.
__global__ __launch_bounds__(256, 3) void k_ffn1(
    const __hip_bfloat16* __restrict__ xb, const __hip_bfloat16* __restrict__ wb1,
    const __hip_bfloat16* __restrict__ wb3,
    const float* __restrict__ w2, __hip_bfloat16* __restrict__ wb2,
    const int* __restrict__ tok, const float* __restrict__ wgt,
    const int* __restrict__ counts, const int* __restrict__ offs,
    __hip_bfloat16* __restrict__ act)
{
    int tid = threadIdx.x;
    if (blockIdx.z == 0) {   // w2 conversion role — dispatched first, hides under GEMM
        size_t gid = ((size_t)(blockIdx.y * gridDim.x + blockIdx.x) * 256 + tid);
        size_t stride = (size_t)gridDim.x * gridDim.y * 256;
        for (size_t i = gid; i < (size_t)NWT; i += stride)
            cvt8(w2 + i * 8, wb2 + i * 8);
        return;
    }
    int e = blockIdx.z - 1;
    int cnt = counts[e];
    int m0 = blockIdx.y * 128;
    if (m0 >= cnt) return;
    int f0 = blockIdx.x * 64;
    __shared__ __align__(16) __hip_bfloat16 sX[128 * BK];   // 16 KB, 16 chunks
    __shared__ __align__(16) __hip_bfloat16 sW1[64 * BK];   // 8 KB, 8 chunks
    __shared__ __align__(16) __hip_bfloat16 sW3[64 * BK];
    __shared__ int sTok[128];
    __shared__ float sWgt[128];
    if (tid < 128) {
        int row = m0 + tid;
        int rr = (row < cnt) ? row : (cnt - 1);
        sTok[tid] = tok[e * NTOK + rr];
        sWgt[tid] = (row < cnt) ? wgt[e * NTOK + row] : 0.f;
    }
    __syncthreads();

    int wv = tid >> 6, lane = tid & 63;
    int lr = lane >> 3;                       // row-in-chunk 0..7
    int sw8 = (((lane & 7) ^ lr) << 3);       // pre-swizzled elem offset

    const __hip_bfloat16* gx[4];
    __hip_bfloat16* lx[4];
#pragma unroll
    for (int j = 0; j < 4; ++j) {
        int c = 4 * wv + j;
        gx[j] = xb + (size_t)sTok[8 * c + lr] * HDIM + sw8;
        lx[j] = sX + c * 512;
    }
    const __hip_bfloat16* gw1[2]; const __hip_bfloat16* gw3[2];
    __hip_bfloat16* lw1[2]; __hip_bfloat16* lw3[2];
#pragma unroll
    for (int j = 0; j < 2; ++j) {
        int c = 2 * wv + j;
        gw1[j] = wb1 + ((size_t)e * FDIM + f0 + 8 * c + lr) * HDIM + sw8;
        gw3[j] = wb3 + ((size_t)e * FDIM + f0 + 8 * c + lr) * HDIM + sw8;
        lw1[j] = sW1 + c * 512;
        lw3[j] = sW3 + c * 512;
    }

    int colx = lane & 15;
    int swz = (colx & 7) << 4;                // byte swizzle for reads
    int kb0 = (lane >> 4) * 16;               // byte base within row
    f32x4 acc1[2][4] = {}, acc3[2][4] = {};

    for (int k0 = 0; k0 < HDIM; k0 += BK) {
#pragma unroll
        for (int j = 0; j < 4; ++j) gload16(lx[j], gx[j] + k0);
#pragma unroll
        for (int j = 0; j < 2; ++j) {
            gload16(lw1[j], gw1[j] + k0);
            gload16(lw3[j], gw3[j] + k0);
        }
        __syncthreads();
#pragma unroll
        for (int ks = 0; ks < 2; ++ks) {
            int off = ((kb0 + ks * 64) ^ swz) >> 1;   // elem offset in row
            bf16x8 a_[2];
#pragma unroll
            for (int m = 0; m < 2; ++m) {
                int row = 32 * wv + m * 16 + colx;
                a_[m] = *(const bf16x8*)&sX[(row << 6) + off];
            }
#pragma unroll
            for (int f = 0; f < 4; ++f) {
                int row = f * 16 + colx;
                bf16x8 b1 = *(const bf16x8*)&sW1[(row << 6) + off];
                bf16x8 b3 = *(const bf16x8*)&sW3[(row << 6) + off];
#pragma unroll
                for (int m = 0; m < 2; ++m) {
                    acc1[m][f] = __builtin_amdgcn_mfma_f32_16x16x32_bf16(a_[m], b1, acc1[m][f], 0, 0, 0);
                    acc3[m][f] = __builtin_amdgcn_mfma_f32_16x16x32_bf16(a_[m], b3, acc3[m][f], 0, 0, 0);
                }
            }
        }
        __syncthreads();
    }
    int soff = offs[e];
    int lane4 = (lane >> 4) * 4;
#pragma unroll
    for (int m = 0; m < 2; ++m) {
        int rbase = 32 * wv + m * 16 + lane4;
#pragma unroll
        for (int q = 0; q < 4; ++q) {
            int rloc = rbase + q;
            if (m0 + rloc < cnt) {
                float wgtv = sWgt[rloc];
#pragma unroll
                for (int f = 0; f < 4; ++f) {
                    float hv = acc1[m][f][q], gv = acc3[m][f][q];
                    float av = hv / (1.f + expf(-hv)) * gv * wgtv;
                    act[(size_t)(soff + m0 + rloc) * FDIM + f0 + f * 16 + colx] =
                        (__hip_bfloat16)av;
                }
            }
        }
    }
}

// ---------------- K7: grouped GEMM phase 2: out += act @ w2^T ---------------
// r11-proven geometry; K-split x8 (blockIdx.z = e*8 + chunk, KCH=448).
__global__ __launch_bounds__(256, 4) void k_ffn2(
    const __hip_bfloat16* __restrict__ act, const __hip_bfloat16* __restrict__ wb2,
    const int* __restrict__ tok, const int* __restrict__ counts,
    const int* __restrict__ offs, float* __restrict__ out)
{
    int z = blockIdx.z;
    int e = z >> 3;
    int kbase = (z & 7) * KCH;
    int cnt = counts[e];
    int m0 = blockIdx.y * 128;
    if (m0 >= cnt) return;
    int h0 = blockIdx.x * 64;
    int tid = threadIdx.x;
    __shared__ __align__(16) __hip_bfloat16 sA[128 * BK];   // 16 KB
    __shared__ __align__(16) __hip_bfloat16 sB[64 * BK];    // 8 KB
    __shared__ int sTok[128];
    if (tid < 128) {
        int row = m0 + tid;
        sTok[tid] = (row < cnt) ? tok[e * NTOK + row] : 0;
    }
    __syncthreads();
    int soff = offs[e];
    int wv = tid >> 6, lane = tid & 63;
    int lr = lane >> 3;
    int sw8 = (((lane & 7) ^ lr) << 3);

    const __hip_bfloat16* ga[4];
    __hip_bfloat16* la[4];
#pragma unroll
    for (int j = 0; j < 4; ++j) {
        int c = 4 * wv + j;
        int trow = 8 * c + lr;
        int arow = (m0 + trow < cnt) ? (m0 + trow) : (cnt - 1);
        ga[j] = act + (size_t)(soff + arow) * FDIM + kbase + sw8;
        la[j] = sA + c * 512;
    }
    const __hip_bfloat16* gb[2];
    __hip_bfloat16* lb[2];
#pragma unroll
    for (int j = 0; j < 2; ++j) {
        int c = 2 * wv + j;
        gb[j] = wb2 + ((size_t)e * HDIM + h0 + 8 * c + lr) * FDIM + kbase + sw8;
        lb[j] = sB + c * 512;
    }

    int colx = lane & 15;
    int swz = (colx & 7) << 4;
    int kb0 = (lane >> 4) * 16;
    f32x4 acc[2][4] = {};

    for (int k0 = 0; k0 < KCH; k0 += BK) {
#pragma unroll
        for (int j = 0; j < 4; ++j) gload16(la[j], ga[j] + k0);
#pragma unroll
        for (int j = 0; j < 2; ++j) gload16(lb[j], gb[j] + k0);
        __syncthreads();
#pragma unroll
        for (int ks = 0; ks < 2; ++ks) {
            int off = ((kb0 + ks * 64) ^ swz) >> 1;
            bf16x8 a_[2];
#pragma unroll
            for (int m = 0; m < 2; ++m) {
                int row = 32 * wv + m * 16 + colx;
                a_[m] = *(const bf16x8*)&sA[(row << 6) + off];
            }
#pragma unroll
            for (int f = 0; f < 4; ++f) {
                int row = f * 16 + colx;
                bf16x8 b = *(const bf16x8*)&sB[(row << 6) + off];
#pragma unroll
                for (int m = 0; m < 2; ++m)
                    acc[m][f] = __builtin_amdgcn_mfma_f32_16x16x32_bf16(a_[m], b, acc[m][f], 0, 0, 0);
            }
        }
        __syncthreads();
    }
    int lane4 = (lane >> 4) * 4;
#pragma unroll
    for (int m = 0; m < 2; ++m) {
        int rbase = 32 * wv + m * 16 + lane4;
#pragma unroll
        for (int q = 0; q < 4; ++q) {
            int rloc = rbase + q;
            if (m0 + rloc < cnt) {
                int t = sTok[rloc];
#pragma unroll
                for (int f = 0; f < 4; ++f)
                    atomicAdd(&out[(size_t)t * HDIM + h0 + f * 16 + colx], acc[m][f][q]);
            }
        }
    }
}

extern "C" void kernel_launch(void* const* d_in, const int* in_sizes, int n_in,
                              void* d_out, int out_size, void* d_ws, size_t ws_size,
                              hipStream_t stream)
{
    const float* x    = (const float*)d_in[0];
    const float* attn = (const float*)d_in[1];
    const float* gw   = (const float*)d_in[2];
    const float* w1   = (const float*)d_in[3];
    const float* w2   = (const float*)d_in[4];
    const float* w3   = (const float*)d_in[5];
    float* out = (float*)d_out;
    float* logits = out + (size_t)NTOK * HDIM;

    char* ws = (char*)d_ws;
    float* l1     = (float*)(ws + 0);
    float* scores = (float*)(ws + 8192);
    int*   sel0   = (int*)(ws + 16384);
    int*   sel1   = (int*)(ws + 24576);
    float* rw0    = (float*)(ws + 32768);
    float* rw1    = (float*)(ws + 40960);
    float* w0f    = (float*)(ws + 49152);
    float* w1f    = (float*)(ws + 57344);
    int*   counts = (int*)(ws + 65536);
    int*   offs   = (int*)(ws + 65600);
    int*   tok    = (int*)(ws + 73728);
    float* wgt    = (float*)(ws + 143360);
    __hip_bfloat16* act = (__hip_bfloat16*)(ws + 1048576);      // <= 29.4 MB
    __hip_bfloat16* xb  = (__hip_bfloat16*)(ws + 33554432);     // 4 MB
    __hip_bfloat16* wb1 = (__hip_bfloat16*)(ws + 67108864);     // 58.7 MB
    __hip_bfloat16* wb3 = (__hip_bfloat16*)(ws + 134217728);    // 58.7 MB
    __hip_bfloat16* wb2 = (__hip_bfloat16*)(ws + 201326592);    // 58.7 MB

    k_prep<<<4096, 256, 0, stream>>>(x, w1, w3, (float4*)out, xb, wb1, wb3);
    k_router<<<NTOK / 4, 256, 0, stream>>>(x, gw, logits, l1, sel0, sel1, rw0, rw1);
    k_attn<<<NTOK, 256, 0, stream>>>(attn, l1, scores);
    k_rank<<<NTOK / 256, 256, 0, stream>>>(scores, rw0, rw1, w0f, w1f);
    k_build<<<1, 512, 0, stream>>>(sel0, sel1, w0f, w1f, tok, wgt, counts, offs);
    k_ffn1<<<dim3(FDIM / 64, NTOK / 128, NEXP + 1), 256, 0, stream>>>(
        xb, wb1, wb3, w2, wb2, tok, wgt, counts, offs, act);
    k_ffn2<<<dim3(HDIM / 64, NTOK / 128, NEXP * KSPLIT), 256, 0, stream>>>(
        act, wb2, tok, counts, offs, out);
}

// Round 21
// 407.470 us; speedup vs baseline: 1.0915x; 1.0915x over previous
//
#include <hip/hip_runtime.h>
#include <hip/hip_bf16.h>
#include <math.h>

#define NTOK 2048
#define HDIM 1024
#define NEXP 8
#define FDIM 3584
#define NHEADS 16
#define NLOW 204
#define NHIGH 204
#define BK 64
#define KSPLIT 4
#define KCH (FDIM / KSPLIT)   // 896

typedef __bf16 bf16x8 __attribute__((ext_vector_type(8)));
typedef float f32x4 __attribute__((ext_vector_type(4)));

// async global->LDS, 16B per lane; LDS dest wave-uniform base + lane*16
__device__ __forceinline__ void gload16(__hip_bfloat16* lds, const __hip_bfloat16* g)
{
    __builtin_amdgcn_global_load_lds(
        (const __attribute__((address_space(1))) unsigned int*)g,
        (__attribute__((address_space(3))) unsigned int*)lds, 16, 0, 0);
}

__device__ __forceinline__ void cvt8(const float* __restrict__ s,
                                     __hip_bfloat16* __restrict__ d)
{
    float4 a = *(const float4*)s;
    float4 b = *(const float4*)(s + 4);
    bf16x8 v;
    v[0] = (__bf16)a.x; v[1] = (__bf16)a.y; v[2] = (__bf16)a.z; v[3] = (__bf16)a.w;
    v[4] = (__bf16)b.x; v[5] = (__bf16)b.y; v[6] = (__bf16)b.z; v[7] = (__bf16)b.w;
    *(bf16x8*)d = v;
}

// ---------------- K0: fused prep: zero(out) + x->bf16 + w1->bf16 + w3->bf16 --
#define NZ   (NTOK * HDIM / 4)          // float4 zero stores
#define NX   (NTOK * HDIM / 8)          // x cvt8 units
#define NWT  (NEXP * FDIM * HDIM / 8)   // per-weight cvt8 units
__global__ __launch_bounds__(256) void k_prep(
    const float* __restrict__ x, const float* __restrict__ w1,
    const float* __restrict__ w3, float4* __restrict__ outz,
    __hip_bfloat16* __restrict__ xb, __hip_bfloat16* __restrict__ wb1,
    __hip_bfloat16* __restrict__ wb3)
{
    size_t gid = (size_t)blockIdx.x * 256 + threadIdx.x;
    size_t stride = (size_t)gridDim.x * 256;
    size_t total = (size_t)NZ + NX + 2 * (size_t)NWT;
    for (size_t i = gid; i < total; i += stride) {
        if (i < NZ) {
            outz[i] = make_float4(0.f, 0.f, 0.f, 0.f);
        } else if (i < (size_t)NZ + NX) {
            size_t j = (i - NZ) * 8;
            cvt8(x + j, xb + j);
        } else if (i < (size_t)NZ + NX + NWT) {
            size_t j = (i - NZ - NX) * 8;
            cvt8(w1 + j, wb1 + j);
        } else {
            size_t j = (i - NZ - NX - NWT) * 8;
            cvt8(w3 + j, wb3 + j);
        }
    }
}

// ---------------- K1: router logits + softmax top2 + L1 norm ----------------
__global__ __launch_bounds__(256) void k_router(
    const float* __restrict__ x, const float* __restrict__ gw,
    float* __restrict__ logits, float* __restrict__ l1,
    int* __restrict__ sel0, int* __restrict__ sel1,
    float* __restrict__ rw0, float* __restrict__ rw1)
{
    __shared__ float sgw[NEXP * HDIM];
    int tid = threadIdx.x;
    for (int i = tid; i < NEXP * HDIM; i += 256) sgw[i] = gw[i];
    __syncthreads();
    int wv = tid >> 6, lane = tid & 63;
    int t = blockIdx.x * 4 + wv;
    const float* xr = x + (size_t)t * HDIM;
    float acc[NEXP];
#pragma unroll
    for (int e = 0; e < NEXP; ++e) acc[e] = 0.f;
    float al1 = 0.f;
    for (int h = lane; h < HDIM; h += 64) {
        float xv = xr[h];
        al1 += fabsf(xv);
#pragma unroll
        for (int e = 0; e < NEXP; ++e) acc[e] += xv * sgw[e * HDIM + h];
    }
#pragma unroll
    for (int off = 32; off > 0; off >>= 1) {
#pragma unroll
        for (int e = 0; e < NEXP; ++e) acc[e] += __shfl_xor(acc[e], off);
        al1 += __shfl_xor(al1, off);
    }
    if (lane < NEXP) logits[t * NEXP + lane] = acc[lane];
    if (lane == 0) {
        l1[t] = al1;
        float m = acc[0];
#pragma unroll
        for (int e = 1; e < NEXP; ++e) m = fmaxf(m, acc[e]);
        float p[NEXP], s = 0.f;
#pragma unroll
        for (int e = 0; e < NEXP; ++e) { p[e] = expf(acc[e] - m); s += p[e]; }
        float inv = 1.f / s;
        float b0 = -1.f, b1 = -1.f; int i0 = 0, i1 = 0;
#pragma unroll
        for (int e = 0; e < NEXP; ++e) {
            float r = p[e] * inv;
            if (r > b0) { b1 = b0; i1 = i0; b0 = r; i0 = e; }
            else if (r > b1) { b1 = r; i1 = e; }
        }
        sel0[t] = i0; sel1[t] = i1; rw0[t] = b0; rw1[t] = b1;
    }
}

// ---------------- K2: attention-based token scores ----------------
__global__ __launch_bounds__(256) void k_attn(
    const float* __restrict__ attn, const float* __restrict__ l1,
    float* __restrict__ scores)
{
    int i = blockIdx.x, tid = threadIdx.x;
    float acc = 0.f;
    for (int h = 0; h < NHEADS; ++h) {
        const float4* p = (const float4*)(attn + ((size_t)h * NTOK + i) * NTOK);
        for (int j = tid; j < NTOK / 4; j += 256) {
            float4 v = p[j];
            acc += v.x + v.y + v.z + v.w;
        }
    }
    __shared__ float red[256];
    red[tid] = acc; __syncthreads();
    for (int s = 128; s > 0; s >>= 1) {
        if (tid < s) red[tid] += red[tid + s];
        __syncthreads();
    }
    if (tid == 0) scores[i] = red[0] / (16.f * (float)(NTOK - i)) * l1[i];
}

// ---------------- K3: exact stable-rank top-k masks + final routing weights --
__global__ __launch_bounds__(256) void k_rank(
    const float* __restrict__ scores, const float* __restrict__ rw0,
    const float* __restrict__ rw1, float* __restrict__ w0f, float* __restrict__ w1f)
{
    __shared__ float s[NTOK];
    int tid = threadIdx.x;
    for (int i = tid; i < NTOK; i += 256) s[i] = scores[i];
    __syncthreads();
    int t = blockIdx.x * 256 + tid;
    float st = s[t];
    int cl = 0, ch = 0;
    for (int j = 0; j < NTOK; ++j) {
        float sj = s[j];
        int tie = (sj == st) && (j < t);
        cl += (sj < st) || tie;
        ch += (sj > st) || tie;
    }
    bool in_low = cl < NLOW, keep = ch < NHIGH;
    float a = rw0[t], b = rw1[t];
    float n0 = 1.f, n1 = (b < 0.5f * a) ? 0.f : 1.f;
    if (in_low) { n0 = 0.f; n1 = 0.f; }
    if (keep)   { n0 = 1.f; n1 = 1.f; }
    a *= n0; b *= n1;
    float d = a + b;
    if (d > 0.f) { a /= d; b /= d; }
    w0f[t] = a; w1f[t] = b;
}

// ---------------- K4: per-expert token list build (deterministic) ----------
__global__ __launch_bounds__(512) void k_build(
    const int* __restrict__ sel0, const int* __restrict__ sel1,
    const float* __restrict__ w0f, const float* __restrict__ w1f,
    int* __restrict__ tok, float* __restrict__ wgt,
    int* __restrict__ counts, int* __restrict__ offs)
{
    int tid = threadIdx.x;
    int e = tid >> 6, lane = tid & 63;
    unsigned long long below = (1ull << lane) - 1ull;
    int base = 0;
    for (int r = 0; r < NTOK / 64; ++r) {
        int t = r * 64 + lane;
        bool f0 = (sel0[t] == e) && (w0f[t] > 0.f);
        unsigned long long m0 = __ballot(f0);
        if (f0) {
            int pos = base + __popcll(m0 & below);
            tok[e * NTOK + pos] = t; wgt[e * NTOK + pos] = w0f[t];
        }
        base += __popcll(m0);
        bool f1 = (sel1[t] == e) && (w1f[t] > 0.f);
        unsigned long long m1 = __ballot(f1);
        if (f1) {
            int pos = base + __popcll(m1 & below);
            tok[e * NTOK + pos] = t; wgt[e * NTOK + pos] = w1f[t];
        }
        base += __popcll(m1);
    }
    if (lane == 0) counts[e] = base;
    __syncthreads();
    if (tid == 0) {
        int o = 0;
        for (int i = 0; i < NEXP; ++i) { offs[i] = o; o += counts[i]; }
    }
}

// ---------------- K6: grouped GEMM phase 1 (+ w2 conversion at z==0) --------
// r11-proven geometry: 128M x 64F tile, BK=64, 4 waves (32 M-rows x 64 F each),
// single-buffered LDS via global_load_lds, XOR-swizzle. blockIdx.z==0 blocks
// (dispatched FIRST) convert w2->bf16; GEMM blocks use e = z-1.
__global__ __launch_bounds__(256, 3) void k_ffn1(
    const __hip_bfloat16* __restrict__ xb, const __hip_bfloat16* __restrict__ wb1,
    const __hip_bfloat16* __restrict__ wb3,
    const float* __restrict__ w2, __hip_bfloat16* __restrict__ wb2,
    const int* __restrict__ tok, const float* __restrict__ wgt,
    const int* __restrict__ counts, const int* __restrict__ offs,
    __hip_bfloat16* __restrict__ act)
{
    int tid = threadIdx.x;
    if (blockIdx.z == 0) {   // w2 conversion role — dispatched first, hides under GEMM
        size_t gid = ((size_t)(blockIdx.y * gridDim.x + blockIdx.x) * 256 + tid);
        size_t stride = (size_t)gridDim.x * gridDim.y * 256;
        for (size_t i = gid; i < (size_t)NWT; i += stride)
            cvt8(w2 + i * 8, wb2 + i * 8);
        return;
    }
    int e = blockIdx.z - 1;
    int cnt = counts[e];
    int m0 = blockIdx.y * 128;
    if (m0 >= cnt) return;
    int f0 = blockIdx.x * 64;
    __shared__ __align__(16) __hip_bfloat16 sX[128 * BK];   // 16 KB, 16 chunks
    __shared__ __align__(16) __hip_bfloat16 sW1[64 * BK];   // 8 KB, 8 chunks
    __shared__ __align__(16) __hip_bfloat16 sW3[64 * BK];
    __shared__ int sTok[128];
    __shared__ float sWgt[128];
    if (tid < 128) {
        int row = m0 + tid;
        int rr = (row < cnt) ? row : (cnt - 1);
        sTok[tid] = tok[e * NTOK + rr];
        sWgt[tid] = (row < cnt) ? wgt[e * NTOK + row] : 0.f;
    }
    __syncthreads();

    int wv = tid >> 6, lane = tid & 63;
    int lr = lane >> 3;                       // row-in-chunk 0..7
    int sw8 = (((lane & 7) ^ lr) << 3);       // pre-swizzled elem offset

    const __hip_bfloat16* gx[4];
    __hip_bfloat16* lx[4];
#pragma unroll
    for (int j = 0; j < 4; ++j) {
        int c = 4 * wv + j;
        gx[j] = xb + (size_t)sTok[8 * c + lr] * HDIM + sw8;
        lx[j] = sX + c * 512;
    }
    const __hip_bfloat16* gw1[2]; const __hip_bfloat16* gw3[2];
    __hip_bfloat16* lw1[2]; __hip_bfloat16* lw3[2];
#pragma unroll
    for (int j = 0; j < 2; ++j) {
        int c = 2 * wv + j;
        gw1[j] = wb1 + ((size_t)e * FDIM + f0 + 8 * c + lr) * HDIM + sw8;
        gw3[j] = wb3 + ((size_t)e * FDIM + f0 + 8 * c + lr) * HDIM + sw8;
        lw1[j] = sW1 + c * 512;
        lw3[j] = sW3 + c * 512;
    }

    int colx = lane & 15;
    int swz = (colx & 7) << 4;                // byte swizzle for reads
    int kb0 = (lane >> 4) * 16;               // byte base within row
    f32x4 acc1[2][4] = {}, acc3[2][4] = {};

    for (int k0 = 0; k0 < HDIM; k0 += BK) {
#pragma unroll
        for (int j = 0; j < 4; ++j) gload16(lx[j], gx[j] + k0);
#pragma unroll
        for (int j = 0; j < 2; ++j) {
            gload16(lw1[j], gw1[j] + k0);
            gload16(lw3[j], gw3[j] + k0);
        }
        __syncthreads();
#pragma unroll
        for (int ks = 0; ks < 2; ++ks) {
            int off = ((kb0 + ks * 64) ^ swz) >> 1;   // elem offset in row
            bf16x8 a_[2];
#pragma unroll
            for (int m = 0; m < 2; ++m) {
                int row = 32 * wv + m * 16 + colx;
                a_[m] = *(const bf16x8*)&sX[(row << 6) + off];
            }
#pragma unroll
            for (int f = 0; f < 4; ++f) {
                int row = f * 16 + colx;
                bf16x8 b1 = *(const bf16x8*)&sW1[(row << 6) + off];
                bf16x8 b3 = *(const bf16x8*)&sW3[(row << 6) + off];
#pragma unroll
                for (int m = 0; m < 2; ++m) {
                    acc1[m][f] = __builtin_amdgcn_mfma_f32_16x16x32_bf16(a_[m], b1, acc1[m][f], 0, 0, 0);
                    acc3[m][f] = __builtin_amdgcn_mfma_f32_16x16x32_bf16(a_[m], b3, acc3[m][f], 0, 0, 0);
                }
            }
        }
        __syncthreads();
    }
    int soff = offs[e];
    int lane4 = (lane >> 4) * 4;
#pragma unroll
    for (int m = 0; m < 2; ++m) {
        int rbase = 32 * wv + m * 16 + lane4;
#pragma unroll
        for (int q = 0; q < 4; ++q) {
            int rloc = rbase + q;
            if (m0 + rloc < cnt) {
                float wgtv = sWgt[rloc];
#pragma unroll
                for (int f = 0; f < 4; ++f) {
                    float hv = acc1[m][f][q], gv = acc3[m][f][q];
                    float av = hv / (1.f + expf(-hv)) * gv * wgtv;
                    act[(size_t)(soff + m0 + rloc) * FDIM + f0 + f * 16 + colx] =
                        (__hip_bfloat16)av;
                }
            }
        }
    }
}

// ---------------- K7: grouped GEMM phase 2: out += act @ w2^T ---------------
// r11-proven geometry; K-split x4 (blockIdx.z = e*4 + chunk).
__global__ __launch_bounds__(256, 4) void k_ffn2(
    const __hip_bfloat16* __restrict__ act, const __hip_bfloat16* __restrict__ wb2,
    const int* __restrict__ tok, const int* __restrict__ counts,
    const int* __restrict__ offs, float* __restrict__ out)
{
    int z = blockIdx.z;
    int e = z >> 2;
    int kbase = (z & 3) * KCH;
    int cnt = counts[e];
    int m0 = blockIdx.y * 128;
    if (m0 >= cnt) return;
    int h0 = blockIdx.x * 64;
    int tid = threadIdx.x;
    __shared__ __align__(16) __hip_bfloat16 sA[128 * BK];   // 16 KB
    __shared__ __align__(16) __hip_bfloat16 sB[64 * BK];    // 8 KB
    __shared__ int sTok[128];
    if (tid < 128) {
        int row = m0 + tid;
        sTok[tid] = (row < cnt) ? tok[e * NTOK + row] : 0;
    }
    __syncthreads();
    int soff = offs[e];
    int wv = tid >> 6, lane = tid & 63;
    int lr = lane >> 3;
    int sw8 = (((lane & 7) ^ lr) << 3);

    const __hip_bfloat16* ga[4];
    __hip_bfloat16* la[4];
#pragma unroll
    for (int j = 0; j < 4; ++j) {
        int c = 4 * wv + j;
        int trow = 8 * c + lr;
        int arow = (m0 + trow < cnt) ? (m0 + trow) : (cnt - 1);
        ga[j] = act + (size_t)(soff + arow) * FDIM + kbase + sw8;
        la[j] = sA + c * 512;
    }
    const __hip_bfloat16* gb[2];
    __hip_bfloat16* lb[2];
#pragma unroll
    for (int j = 0; j < 2; ++j) {
        int c = 2 * wv + j;
        gb[j] = wb2 + ((size_t)e * HDIM + h0 + 8 * c + lr) * FDIM + kbase + sw8;
        lb[j] = sB + c * 512;
    }

    int colx = lane & 15;
    int swz = (colx & 7) << 4;
    int kb0 = (lane >> 4) * 16;
    f32x4 acc[2][4] = {};

    for (int k0 = 0; k0 < KCH; k0 += BK) {
#pragma unroll
        for (int j = 0; j < 4; ++j) gload16(la[j], ga[j] + k0);
#pragma unroll
        for (int j = 0; j < 2; ++j) gload16(lb[j], gb[j] + k0);
        __syncthreads();
#pragma unroll
        for (int ks = 0; ks < 2; ++ks) {
            int off = ((kb0 + ks * 64) ^ swz) >> 1;
            bf16x8 a_[2];
#pragma unroll
            for (int m = 0; m < 2; ++m) {
                int row = 32 * wv + m * 16 + colx;
                a_[m] = *(const bf16x8*)&sA[(row << 6) + off];
            }
#pragma unroll
            for (int f = 0; f < 4; ++f) {
                int row = f * 16 + colx;
                bf16x8 b = *(const bf16x8*)&sB[(row << 6) + off];
#pragma unroll
                for (int m = 0; m < 2; ++m)
                    acc[m][f] = __builtin_amdgcn_mfma_f32_16x16x32_bf16(a_[m], b, acc[m][f], 0, 0, 0);
            }
        }
        __syncthreads();
    }
    int lane4 = (lane >> 4) * 4;
#pragma unroll
    for (int m = 0; m < 2; ++m) {
        int rbase = 32 * wv + m * 16 + lane4;
#pragma unroll
        for (int q = 0; q < 4; ++q) {
            int rloc = rbase + q;
            if (m0 + rloc < cnt) {
                int t = sTok[rloc];
#pragma unroll
                for (int f = 0; f < 4; ++f)
                    atomicAdd(&out[(size_t)t * HDIM + h0 + f * 16 + colx], acc[m][f][q]);
            }
        }
    }
}

extern "C" void kernel_launch(void* const* d_in, const int* in_sizes, int n_in,
                              void* d_out, int out_size, void* d_ws, size_t ws_size,
                              hipStream_t stream)
{
    const float* x    = (const float*)d_in[0];
    const float* attn = (const float*)d_in[1];
    const float* gw   = (const float*)d_in[2];
    const float* w1   = (const float*)d_in[3];
    const float* w2   = (const float*)d_in[4];
    const float* w3   = (const float*)d_in[5];
    float* out = (float*)d_out;
    float* logits = out + (size_t)NTOK * HDIM;

    char* ws = (char*)d_ws;
    float* l1     = (float*)(ws + 0);
    float* scores = (float*)(ws + 8192);
    int*   sel0   = (int*)(ws + 16384);
    int*   sel1   = (int*)(ws + 24576);
    float* rw0    = (float*)(ws + 32768);
    float* rw1    = (float*)(ws + 40960);
    float* w0f    = (float*)(ws + 49152);
    float* w1f    = (float*)(ws + 57344);
    int*   counts = (int*)(ws + 65536);
    int*   offs   = (int*)(ws + 65600);
    int*   tok    = (int*)(ws + 73728);
    float* wgt    = (float*)(ws + 143360);
    __hip_bfloat16* act = (__hip_bfloat16*)(ws + 1048576);      // <= 29.4 MB
    __hip_bfloat16* xb  = (__hip_bfloat16*)(ws + 33554432);     // 4 MB
    __hip_bfloat16* wb1 = (__hip_bfloat16*)(ws + 67108864);     // 58.7 MB
    __hip_bfloat16* wb3 = (__hip_bfloat16*)(ws + 134217728);    // 58.7 MB
    __hip_bfloat16* wb2 = (__hip_bfloat16*)(ws + 201326592);    // 58.7 MB

    k_prep<<<4096, 256, 0, stream>>>(x, w1, w3, (float4*)out, xb, wb1, wb3);
    k_router<<<NTOK / 4, 256, 0, stream>>>(x, gw, logits, l1, sel0, sel1, rw0, rw1);
    k_attn<<<NTOK, 256, 0, stream>>>(attn, l1, scores);
    k_rank<<<NTOK / 256, 256, 0, stream>>>(scores, rw0, rw1, w0f, w1f);
    k_build<<<1, 512, 0, stream>>>(sel0, sel1, w0f, w1f, tok, wgt, counts, offs);
    k_ffn1<<<dim3(FDIM / 64, NTOK / 128, NEXP + 1), 256, 0, stream>>>(
        xb, wb1, wb3, w2, wb2, tok, wgt, counts, offs, act);
    k_ffn2<<<dim3(HDIM / 64, NTOK / 128, NEXP * KSPLIT), 256, 0, stream>>>(
        act, wb2, tok, counts, offs, out);
}

// Round 22
// 400.547 us; speedup vs baseline: 1.1103x; 1.0173x over previous
//
#include <hip/hip_runtime.h>
#include <hip/hip_bf16.h>
#include <math.h>

#define NTOK 2048
#define HDIM 1024
#define NEXP 8
#define FDIM 3584
#define NHEADS 16
#define NLOW 204
#define NHIGH 204
#define BK1 32     // ffn1 K-step (reg-staged, LDST-padded LDS)
#define LDST 40    // ffn1 padded LDS row stride in bf16 elems
#define BK2 64     // ffn2 K-step (gload_lds, swizzled)
#define KSPLIT 4
#define KCH (FDIM / KSPLIT)   // 896

typedef __bf16 bf16x8 __attribute__((ext_vector_type(8)));
typedef float f32x4 __attribute__((ext_vector_type(4)));

// async global->LDS, 16B per lane; LDS dest wave-uniform base + lane*16
__device__ __forceinline__ void gload16(__hip_bfloat16* lds, const __hip_bfloat16* g)
{
    __builtin_amdgcn_global_load_lds(
        (const __attribute__((address_space(1))) unsigned int*)g,
        (__attribute__((address_space(3))) unsigned int*)lds, 16, 0, 0);
}

__device__ __forceinline__ void cvt8(const float* __restrict__ s,
                                     __hip_bfloat16* __restrict__ d)
{
    float4 a = *(const float4*)s;
    float4 b = *(const float4*)(s + 4);
    bf16x8 v;
    v[0] = (__bf16)a.x; v[1] = (__bf16)a.y; v[2] = (__bf16)a.z; v[3] = (__bf16)a.w;
    v[4] = (__bf16)b.x; v[5] = (__bf16)b.y; v[6] = (__bf16)b.z; v[7] = (__bf16)b.w;
    *(bf16x8*)d = v;
}

struct F16v { float4 a, b, c, d; };
__device__ __forceinline__ F16v ld16(const float* __restrict__ p)
{
    F16v v;
    v.a = *(const float4*)p;
    v.b = *(const float4*)(p + 4);
    v.c = *(const float4*)(p + 8);
    v.d = *(const float4*)(p + 12);
    return v;
}
__device__ __forceinline__ void st16(__hip_bfloat16* dst, const F16v& v)
{
    bf16x8 lo, hi;
    lo[0] = (__bf16)v.a.x; lo[1] = (__bf16)v.a.y; lo[2] = (__bf16)v.a.z; lo[3] = (__bf16)v.a.w;
    lo[4] = (__bf16)v.b.x; lo[5] = (__bf16)v.b.y; lo[6] = (__bf16)v.b.z; lo[7] = (__bf16)v.b.w;
    hi[0] = (__bf16)v.c.x; hi[1] = (__bf16)v.c.y; hi[2] = (__bf16)v.c.z; hi[3] = (__bf16)v.c.w;
    hi[4] = (__bf16)v.d.x; hi[5] = (__bf16)v.d.y; hi[6] = (__bf16)v.d.z; hi[7] = (__bf16)v.d.w;
    *(bf16x8*)dst = lo;
    *(bf16x8*)(dst + 8) = hi;
}

// ---------------- K0: minimal prep: zero(out) + x->bf16 --------------------
#define NZ   (NTOK * HDIM / 4)          // float4 zero stores
#define NX   (NTOK * HDIM / 8)          // x cvt8 units
#define NWT  (NEXP * FDIM * HDIM / 8)   // w2 cvt8 units (converted inside ffn1)
__global__ __launch_bounds__(256) void k_prep(
    const float* __restrict__ x, float4* __restrict__ outz,
    __hip_bfloat16* __restrict__ xb)
{
    size_t gid = (size_t)blockIdx.x * 256 + threadIdx.x;
    size_t stride = (size_t)gridDim.x * 256;
    size_t total = (size_t)NZ + NX;
    for (size_t i = gid; i < total; i += stride) {
        if (i < NZ) {
            outz[i] = make_float4(0.f, 0.f, 0.f, 0.f);
        } else {
            size_t j = (i - NZ) * 8;
            cvt8(x + j, xb + j);
        }
    }
}

// ---------------- K1: router logits + softmax top2 + L1 norm ----------------
__global__ __launch_bounds__(256) void k_router(
    const float* __restrict__ x, const float* __restrict__ gw,
    float* __restrict__ logits, float* __restrict__ l1,
    int* __restrict__ sel0, int* __restrict__ sel1,
    float* __restrict__ rw0, float* __restrict__ rw1)
{
    __shared__ float sgw[NEXP * HDIM];
    int tid = threadIdx.x;
    for (int i = tid; i < NEXP * HDIM; i += 256) sgw[i] = gw[i];
    __syncthreads();
    int wv = tid >> 6, lane = tid & 63;
    int t = blockIdx.x * 4 + wv;
    const float* xr = x + (size_t)t * HDIM;
    float acc[NEXP];
#pragma unroll
    for (int e = 0; e < NEXP; ++e) acc[e] = 0.f;
    float al1 = 0.f;
    for (int h = lane; h < HDIM; h += 64) {
        float xv = xr[h];
        al1 += fabsf(xv);
#pragma unroll
        for (int e = 0; e < NEXP; ++e) acc[e] += xv * sgw[e * HDIM + h];
    }
#pragma unroll
    for (int off = 32; off > 0; off >>= 1) {
#pragma unroll
        for (int e = 0; e < NEXP; ++e) acc[e] += __shfl_xor(acc[e], off);
        al1 += __shfl_xor(al1, off);
    }
    if (lane < NEXP) logits[t * NEXP + lane] = acc[lane];
    if (lane == 0) {
        l1[t] = al1;
        float m = acc[0];
#pragma unroll
        for (int e = 1; e < NEXP; ++e) m = fmaxf(m, acc[e]);
        float p[NEXP], s = 0.f;
#pragma unroll
        for (int e = 0; e < NEXP; ++e) { p[e] = expf(acc[e] - m); s += p[e]; }
        float inv = 1.f / s;
        float b0 = -1.f, b1 = -1.f; int i0 = 0, i1 = 0;
#pragma unroll
        for (int e = 0; e < NEXP; ++e) {
            float r = p[e] * inv;
            if (r > b0) { b1 = b0; i1 = i0; b0 = r; i0 = e; }
            else if (r > b1) { b1 = r; i1 = e; }
        }
        sel0[t] = i0; sel1[t] = i1; rw0[t] = b0; rw1[t] = b1;
    }
}

// ---------------- K2: attention-based token scores ----------------
__global__ __launch_bounds__(256) void k_attn(
    const float* __restrict__ attn, const float* __restrict__ l1,
    float* __restrict__ scores)
{
    int i = blockIdx.x, tid = threadIdx.x;
    float acc = 0.f;
    for (int h = 0; h < NHEADS; ++h) {
        const float4* p = (const float4*)(attn + ((size_t)h * NTOK + i) * NTOK);
        for (int j = tid; j < NTOK / 4; j += 256) {
            float4 v = p[j];
            acc += v.x + v.y + v.z + v.w;
        }
    }
    __shared__ float red[256];
    red[tid] = acc; __syncthreads();
    for (int s = 128; s > 0; s >>= 1) {
        if (tid < s) red[tid] += red[tid + s];
        __syncthreads();
    }
    if (tid == 0) scores[i] = red[0] / (16.f * (float)(NTOK - i)) * l1[i];
}

// ---------------- K3: exact stable-rank top-k masks + final routing weights --
__global__ __launch_bounds__(256) void k_rank(
    const float* __restrict__ scores, const float* __restrict__ rw0,
    const float* __restrict__ rw1, float* __restrict__ w0f, float* __restrict__ w1f)
{
    __shared__ float s[NTOK];
    int tid = threadIdx.x;
    for (int i = tid; i < NTOK; i += 256) s[i] = scores[i];
    __syncthreads();
    int t = blockIdx.x * 256 + tid;
    float st = s[t];
    int cl = 0, ch = 0;
    for (int j = 0; j < NTOK; ++j) {
        float sj = s[j];
        int tie = (sj == st) && (j < t);
        cl += (sj < st) || tie;
        ch += (sj > st) || tie;
    }
    bool in_low = cl < NLOW, keep = ch < NHIGH;
    float a = rw0[t], b = rw1[t];
    float n0 = 1.f, n1 = (b < 0.5f * a) ? 0.f : 1.f;
    if (in_low) { n0 = 0.f; n1 = 0.f; }
    if (keep)   { n0 = 1.f; n1 = 1.f; }
    a *= n0; b *= n1;
    float d = a + b;
    if (d > 0.f) { a /= d; b /= d; }
    w0f[t] = a; w1f[t] = b;
}

// ---------------- K4: per-expert token list build (deterministic) ----------
__global__ __launch_bounds__(512) void k_build(
    const int* __restrict__ sel0, const int* __restrict__ sel1,
    const float* __restrict__ w0f, const float* __restrict__ w1f,
    int* __restrict__ tok, float* __restrict__ wgt,
    int* __restrict__ counts, int* __restrict__ offs)
{
    int tid = threadIdx.x;
    int e = tid >> 6, lane = tid & 63;
    unsigned long long below = (1ull << lane) - 1ull;
    int base = 0;
    for (int r = 0; r < NTOK / 64; ++r) {
        int t = r * 64 + lane;
        bool f0 = (sel0[t] == e) && (w0f[t] > 0.f);
        unsigned long long m0 = __ballot(f0);
        if (f0) {
            int pos = base + __popcll(m0 & below);
            tok[e * NTOK + pos] = t; wgt[e * NTOK + pos] = w0f[t];
        }
        base += __popcll(m0);
        bool f1 = (sel1[t] == e) && (w1f[t] > 0.f);
        unsigned long long m1 = __ballot(f1);
        if (f1) {
            int pos = base + __popcll(m1 & below);
            tok[e * NTOK + pos] = t; wgt[e * NTOK + pos] = w1f[t];
        }
        base += __popcll(m1);
    }
    if (lane == 0) counts[e] = base;
    __syncthreads();
    if (tid == 0) {
        int o = 0;
        for (int i = 0; i < NEXP; ++i) { offs[i] = o; o += counts[i]; }
    }
}

// ---------------- K6: phase-1 grouped GEMM (+ w2 conversion at z==0) -------
// r10-proven reg-staged geometry: 128M x 128F tile, 4 waves 2x2, 4x4 frags,
// BK1=32, LDS dbuf (LDST pad), 1-deep reg staging; x from xb (bf16 copy),
// w1/w3 read f32 + converted in-register (no pre-conversion pass needed).
// blockIdx.z==0 blocks (dispatched FIRST) convert w2->bf16 for ffn2.
__global__ __launch_bounds__(256, 2) void k_ffn1(
    const __hip_bfloat16* __restrict__ xb, const float* __restrict__ w1,
    const float* __restrict__ w3,
    const float* __restrict__ w2, __hip_bfloat16* __restrict__ wb2,
    const int* __restrict__ tok, const float* __restrict__ wgt,
    const int* __restrict__ counts, const int* __restrict__ offs,
    __hip_bfloat16* __restrict__ act)
{
    int tid = threadIdx.x;
    if (blockIdx.z == 0) {   // w2 conversion role — overlaps with GEMM blocks
        size_t gid = ((size_t)(blockIdx.y * gridDim.x + blockIdx.x) * 256 + tid);
        size_t stride = (size_t)gridDim.x * gridDim.y * 256;
        for (size_t i = gid; i < (size_t)NWT; i += stride)
            cvt8(w2 + i * 8, wb2 + i * 8);
        return;
    }
    int e = blockIdx.z - 1;
    int cnt = counts[e];
    int m0 = blockIdx.y * 128;
    if (m0 >= cnt) return;
    int f0 = blockIdx.x * 128;
    __shared__ __align__(16) __hip_bfloat16 sX[2][128 * LDST];
    __shared__ __align__(16) __hip_bfloat16 sW1[2][128 * LDST];
    __shared__ __align__(16) __hip_bfloat16 sW3[2][128 * LDST];
    __shared__ int sTok[128];
    __shared__ float sWgt[128];
    if (tid < 128) {
        int row = m0 + tid;
        int rr = (row < cnt) ? row : (cnt - 1);
        sTok[tid] = tok[e * NTOK + rr];
        sWgt[tid] = (row < cnt) ? wgt[e * NTOK + row] : 0.f;
    }
    __syncthreads();

    int r = tid >> 1, c16 = (tid & 1) * 16;
    const __hip_bfloat16* xp = xb + (size_t)sTok[r] * HDIM + c16;
    const float* w1p = w1 + ((size_t)e * FDIM + f0 + r) * HDIM + c16;
    const float* w3p = w3 + ((size_t)e * FDIM + f0 + r) * HDIM + c16;
    int sidx = r * LDST + c16;

    {
        bf16x8 x0 = *(const bf16x8*)xp, x1 = *(const bf16x8*)(xp + 8);
        F16v w0 = ld16(w1p), g0 = ld16(w3p);
        *(bf16x8*)&sX[0][sidx] = x0;
        *(bf16x8*)&sX[0][sidx + 8] = x1;
        st16(&sW1[0][sidx], w0);
        st16(&sW3[0][sidx], g0);
    }
    __syncthreads();

    int wv = tid >> 6, lane = tid & 63;
    int wm = (wv >> 1) * 64, wf = (wv & 1) * 64;
    int col = lane & 15, kfrag = (lane >> 4) * 8;
    f32x4 acc1[4][4] = {}, acc3[4][4] = {};
    int cur = 0;
    for (int k0 = 0; k0 < HDIM; k0 += BK1) {
        bool more = (k0 + BK1) < HDIM;
        bf16x8 xn0, xn1; F16v wn, gn;
        if (more) {
            xn0 = *(const bf16x8*)(xp + k0 + BK1);
            xn1 = *(const bf16x8*)(xp + k0 + BK1 + 8);
            wn = ld16(w1p + k0 + BK1);
            gn = ld16(w3p + k0 + BK1);
        }
        bf16x8 af[4], b1f[4], b3f[4];
#pragma unroll
        for (int m = 0; m < 4; ++m)
            af[m] = *(const bf16x8*)&sX[cur][(wm + m * 16 + col) * LDST + kfrag];
#pragma unroll
        for (int f = 0; f < 4; ++f) {
            b1f[f] = *(const bf16x8*)&sW1[cur][(wf + f * 16 + col) * LDST + kfrag];
            b3f[f] = *(const bf16x8*)&sW3[cur][(wf + f * 16 + col) * LDST + kfrag];
        }
#pragma unroll
        for (int m = 0; m < 4; ++m)
#pragma unroll
            for (int f = 0; f < 4; ++f) {
                acc1[m][f] = __builtin_amdgcn_mfma_f32_16x16x32_bf16(af[m], b1f[f], acc1[m][f], 0, 0, 0);
                acc3[m][f] = __builtin_amdgcn_mfma_f32_16x16x32_bf16(af[m], b3f[f], acc3[m][f], 0, 0, 0);
            }
        if (more) {
            *(bf16x8*)&sX[cur ^ 1][sidx] = xn0;
            *(bf16x8*)&sX[cur ^ 1][sidx + 8] = xn1;
            st16(&sW1[cur ^ 1][sidx], wn);
            st16(&sW3[cur ^ 1][sidx], gn);
        }
        __syncthreads();
        cur ^= 1;
    }
    int soff = offs[e];
#pragma unroll
    for (int m = 0; m < 4; ++m) {
        int mb = wm + m * 16 + (lane >> 4) * 4;
#pragma unroll
        for (int q = 0; q < 4; ++q) {
            int rloc = mb + q;
            if (m0 + rloc < cnt) {
                float wgtv = sWgt[rloc];
#pragma unroll
                for (int f = 0; f < 4; ++f) {
                    float hv = acc1[m][f][q], gv = acc3[m][f][q];
                    float av = hv / (1.f + expf(-hv)) * gv * wgtv;
                    act[(size_t)(soff + m0 + rloc) * FDIM + f0 + wf + f * 16 + col] =
                        (__hip_bfloat16)av;
                }
            }
        }
    }
}

// ---------------- K7: grouped GEMM phase 2: out += act @ w2^T ---------------
// r21-proven geometry: 128M x 64H, BK2=64, gload_lds + XOR-swizzle, KSPLIT=4.
__global__ __launch_bounds__(256, 4) void k_ffn2(
    const __hip_bfloat16* __restrict__ act, const __hip_bfloat16* __restrict__ wb2,
    const int* __restrict__ tok, const int* __restrict__ counts,
    const int* __restrict__ offs, float* __restrict__ out)
{
    int z = blockIdx.z;
    int e = z >> 2;
    int kbase = (z & 3) * KCH;
    int cnt = counts[e];
    int m0 = blockIdx.y * 128;
    if (m0 >= cnt) return;
    int h0 = blockIdx.x * 64;
    int tid = threadIdx.x;
    __shared__ __align__(16) __hip_bfloat16 sA[128 * BK2];   // 16 KB
    __shared__ __align__(16) __hip_bfloat16 sB[64 * BK2];    // 8 KB
    __shared__ int sTok[128];
    if (tid < 128) {
        int row = m0 + tid;
        sTok[tid] = (row < cnt) ? tok[e * NTOK + row] : 0;
    }
    __syncthreads();
    int soff = offs[e];
    int wv = tid >> 6, lane = tid & 63;
    int lr = lane >> 3;
    int sw8 = (((lane & 7) ^ lr) << 3);

    const __hip_bfloat16* ga[4];
    __hip_bfloat16* la[4];
#pragma unroll
    for (int j = 0; j < 4; ++j) {
        int c = 4 * wv + j;
        int trow = 8 * c + lr;
        int arow = (m0 + trow < cnt) ? (m0 + trow) : (cnt - 1);
        ga[j] = act + (size_t)(soff + arow) * FDIM + kbase + sw8;
        la[j] = sA + c * 512;
    }
    const __hip_bfloat16* gb[2];
    __hip_bfloat16* lb[2];
#pragma unroll
    for (int j = 0; j < 2; ++j) {
        int c = 2 * wv + j;
        gb[j] = wb2 + ((size_t)e * HDIM + h0 + 8 * c + lr) * FDIM + kbase + sw8;
        lb[j] = sB + c * 512;
    }

    int colx = lane & 15;
    int swz = (colx & 7) << 4;
    int kb0 = (lane >> 4) * 16;
    f32x4 acc[2][4] = {};

    for (int k0 = 0; k0 < KCH; k0 += BK2) {
#pragma unroll
        for (int j = 0; j < 4; ++j) gload16(la[j], ga[j] + k0);
#pragma unroll
        for (int j = 0; j < 2; ++j) gload16(lb[j], gb[j] + k0);
        __syncthreads();
#pragma unroll
        for (int ks = 0; ks < 2; ++ks) {
            int off = ((kb0 + ks * 64) ^ swz) >> 1;
            bf16x8 a_[2];
#pragma unroll
            for (int m = 0; m < 2; ++m) {
                int row = 32 * wv + m * 16 + colx;
                a_[m] = *(const bf16x8*)&sA[(row << 6) + off];
            }
#pragma unroll
            for (int f = 0; f < 4; ++f) {
                int row = f * 16 + colx;
                bf16x8 b = *(const bf16x8*)&sB[(row << 6) + off];
#pragma unroll
                for (int m = 0; m < 2; ++m)
                    acc[m][f] = __builtin_amdgcn_mfma_f32_16x16x32_bf16(a_[m], b, acc[m][f], 0, 0, 0);
            }
        }
        __syncthreads();
    }
    int lane4 = (lane >> 4) * 4;
#pragma unroll
    for (int m = 0; m < 2; ++m) {
        int rbase = 32 * wv + m * 16 + lane4;
#pragma unroll
        for (int q = 0; q < 4; ++q) {
            int rloc = rbase + q;
            if (m0 + rloc < cnt) {
                int t = sTok[rloc];
#pragma unroll
                for (int f = 0; f < 4; ++f)
                    atomicAdd(&out[(size_t)t * HDIM + h0 + f * 16 + colx], acc[m][f][q]);
            }
        }
    }
}

extern "C" void kernel_launch(void* const* d_in, const int* in_sizes, int n_in,
                              void* d_out, int out_size, void* d_ws, size_t ws_size,
                              hipStream_t stream)
{
    const float* x    = (const float*)d_in[0];
    const float* attn = (const float*)d_in[1];
    const float* gw   = (const float*)d_in[2];
    const float* w1   = (const float*)d_in[3];
    const float* w2   = (const float*)d_in[4];
    const float* w3   = (const float*)d_in[5];
    float* out = (float*)d_out;
    float* logits = out + (size_t)NTOK * HDIM;

    char* ws = (char*)d_ws;
    float* l1     = (float*)(ws + 0);
    float* scores = (float*)(ws + 8192);
    int*   sel0   = (int*)(ws + 16384);
    int*   sel1   = (int*)(ws + 24576);
    float* rw0    = (float*)(ws + 32768);
    float* rw1    = (float*)(ws + 40960);
    float* w0f    = (float*)(ws + 49152);
    float* w1f    = (float*)(ws + 57344);
    int*   counts = (int*)(ws + 65536);
    int*   offs   = (int*)(ws + 65600);
    int*   tok    = (int*)(ws + 73728);
    float* wgt    = (float*)(ws + 143360);
    __hip_bfloat16* act = (__hip_bfloat16*)(ws + 1048576);      // <= 29.4 MB
    __hip_bfloat16* xb  = (__hip_bfloat16*)(ws + 33554432);     // 4 MB
    __hip_bfloat16* wb2 = (__hip_bfloat16*)(ws + 67108864);     // 58.7 MB

    k_prep<<<1024, 256, 0, stream>>>(x, (float4*)out, xb);
    k_router<<<NTOK / 4, 256, 0, stream>>>(x, gw, logits, l1, sel0, sel1, rw0, rw1);
    k_attn<<<NTOK, 256, 0, stream>>>(attn, l1, scores);
    k_rank<<<NTOK / 256, 256, 0, stream>>>(scores, rw0, rw1, w0f, w1f);
    k_build<<<1, 512, 0, stream>>>(sel0, sel1, w0f, w1f, tok, wgt, counts, offs);
    k_ffn1<<<dim3(FDIM / 128, NTOK / 128, NEXP + 1), 256, 0, stream>>>(
        xb, w1, w3, w2, wb2, tok, wgt, counts, offs, act);
    k_ffn2<<<dim3(HDIM / 64, NTOK / 128, NEXP * KSPLIT), 256, 0, stream>>>(
        act, wb2, tok, counts, offs, out);
}